// Round 10
// baseline (1010.003 us; speedup 1.0000x reference)
//
#include <hip/hip_runtime.h>
#include <hip/hip_bf16.h>
#include <hip/hip_cooperative_groups.h>

namespace cg = cooperative_groups;

// SAGE layer via linearity of the message Linear:
//   msum[n] = W_msg · (Σ_{e->n} [nf[src] ‖ ef[e]]) ; bias folded post-mean.
// csr_k (cooperative: zero+Wpack / hist / chunk-sum / scan / bin) ->
// reduce_k (per-node gather, at measured floor) -> node_apply (fused MFMA).
// Fallback to discrete-kernel CSR path if cooperative launch unavailable.

typedef __attribute__((ext_vector_type(8))) short bf16x8;
typedef __attribute__((ext_vector_type(4))) short bf16x4;
typedef __attribute__((ext_vector_type(4))) float f32x4;
typedef __attribute__((ext_vector_type(2))) int i32x2;

__device__ __forceinline__ short f2bf(float f) {
  union { float f; unsigned u; } v; v.f = f;
  unsigned u = v.u;
  u += 0x7fffu + ((u >> 16) & 1u);   // round-to-nearest-even
  return (short)(u >> 16);
}

__device__ __forceinline__ bf16x8 pack8(float4 a, float4 b) {
  bf16x8 r;
  r[0] = f2bf(a.x); r[1] = f2bf(a.y); r[2] = f2bf(a.z); r[3] = f2bf(a.w);
  r[4] = f2bf(b.x); r[5] = f2bf(b.y); r[6] = f2bf(b.z); r[7] = f2bf(b.w);
  return r;
}

__device__ __forceinline__ bf16x4 pack4(f32x4 a) {
  bf16x4 r;
  r[0] = f2bf(a[0]); r[1] = f2bf(a[1]); r[2] = f2bf(a[2]); r[3] = f2bf(a[3]);
  return r;
}

__device__ __forceinline__ void pack_w_block(const float* __restrict__ Wm,
                                             const float* __restrict__ Wa,
                                             short* __restrict__ wpack, int tid) {
#pragma unroll
  for (int j = 0; j < 8; ++j) {
    int id = tid * 8 + j;
    int w = id >> 10, kc = (id >> 8) & 3, nc = (id >> 6) & 3, lane = id & 63;
    int r = lane & 15, g = lane >> 4;
    const float* W = w ? Wa : Wm;
    const float* p = W + (nc * 16 + r) * 128 + kc * 32 + g * 8;
    *(bf16x8*)(wpack + (long)id * 8) = pack8(*(const float4*)p, *(const float4*)(p + 4));
  }
}

// ================= cooperative CSR build =================
__global__ __launch_bounds__(256, 8) void csr_k(
    const float* __restrict__ Wm, const float* __restrict__ Wa,
    short* __restrict__ wpack,
    const int* __restrict__ src, const int* __restrict__ dst,
    int* __restrict__ hist, int* __restrict__ off, int* __restrict__ woff,
    int* __restrict__ parts, i32x2* __restrict__ packed, int N, int E)
{
  cg::grid_group grid = cg::this_grid();
  const int tid = (int)threadIdx.x;
  const int bx = (int)blockIdx.x;
  const int nb = (int)gridDim.x;
  const int gsz = nb * 256;
  const int gid = bx * 256 + tid;

  // ---- ph0: zero hist; block 0 packs W fragments ----
  for (int i = gid; i < N; i += gsz) hist[i] = 0;
  if (bx == 0) pack_w_block(Wm, Wa, wpack, tid);
  grid.sync();

  // ---- ph1: histogram of dst ----
  {
    const int E4 = E >> 2;
    for (int i4 = gid; i4 < E4; i4 += gsz) {
      const int4 d = ((const int4*)dst)[i4];
      atomicAdd(&hist[d.x], 1); atomicAdd(&hist[d.y], 1);
      atomicAdd(&hist[d.z], 1); atomicAdd(&hist[d.w], 1);
    }
    if (bx == 0) {
      int i = (E & ~3) + tid;
      if (i < E) atomicAdd(&hist[dst[i]], 1);
    }
  }
  grid.sync();

  // ---- ph2: per-block chunk sums -> parts ----
  const int per = (N + nb - 1) / nb;
  const int cbeg = bx * per;
  const int cend = min(cbeg + per, N);
  __shared__ int sred[256];
  {
    int s = 0;
    for (int i = cbeg + tid; i < cend; i += 256) s += hist[i];
    sred[tid] = s;
    __syncthreads();
    for (int o = 128; o > 0; o >>= 1) {
      if (tid < o) sred[tid] += sred[tid + o];
      __syncthreads();
    }
    if (tid == 0) parts[bx] = sred[0];
  }
  grid.sync();

  // ---- ph3: block prefix over parts, then chunk exclusive scan -> off/woff ----
  __shared__ int sh[2048];
  __shared__ int blkpref;
  __shared__ int sscan[256];
  for (int i = tid; i < nb; i += 256) sh[i] = parts[i];
  __syncthreads();
  if (tid < 64) {
    int s = 0;
    for (int i = tid; i < bx; i += 64) s += sh[i];
#pragma unroll
    for (int m = 1; m < 64; m <<= 1) s += __shfl_xor(s, m);
    if (tid == 0) blkpref = s;
  }
  __syncthreads();
  {
    const int tper = (per + 255) / 256;
    const int tbeg = cbeg + tid * tper;
    const int tend = min(tbeg + tper, cend);
    int s = 0;
    for (int i = tbeg; i < tend; ++i) s += hist[i];
    sscan[tid] = s;
    __syncthreads();
    for (int o = 1; o < 256; o <<= 1) {
      int y = (tid >= o) ? sscan[tid - o] : 0;
      __syncthreads();
      sscan[tid] += y;
      __syncthreads();
    }
    int run = blkpref + sscan[tid] - s;
    for (int i = tbeg; i < tend; ++i) {
      int h = hist[i];
      off[i] = run; woff[i] = run;
      run += h;
    }
  }
  if (bx == 0 && tid == 0) off[N] = E;
  grid.sync();

  // ---- ph4: bin (eid, src) into CSR order ----
  {
    const int E4 = E >> 2;
    for (int i4 = gid; i4 < E4; i4 += gsz) {
      const int4 d = ((const int4*)dst)[i4];
      const int4 sv = ((const int4*)src)[i4];
      const int e0 = i4 * 4;
      int p; i32x2 v;
      p = atomicAdd(&woff[d.x], 1); v[0] = e0 + 0; v[1] = sv.x; __builtin_nontemporal_store(v, &packed[p]);
      p = atomicAdd(&woff[d.y], 1); v[0] = e0 + 1; v[1] = sv.y; __builtin_nontemporal_store(v, &packed[p]);
      p = atomicAdd(&woff[d.z], 1); v[0] = e0 + 2; v[1] = sv.z; __builtin_nontemporal_store(v, &packed[p]);
      p = atomicAdd(&woff[d.w], 1); v[0] = e0 + 3; v[1] = sv.w; __builtin_nontemporal_store(v, &packed[p]);
    }
    if (bx == 0) {
      int i = (E & ~3) + tid;
      if (i < E) {
        int p = atomicAdd(&woff[dst[i]], 1);
        i32x2 v; v[0] = i; v[1] = src[i];
        __builtin_nontemporal_store(v, &packed[p]);
      }
    }
  }
}

// ================= fallback discrete CSR path =================
__global__ __launch_bounds__(256) void fb_histw_k(
    const float* __restrict__ Wm, const float* __restrict__ Wa,
    short* __restrict__ wpack, const int* __restrict__ dst,
    int* __restrict__ hist, int E, int hist_blocks)
{
  const int bx = (int)blockIdx.x;
  if (bx == 0) { pack_w_block(Wm, Wa, wpack, threadIdx.x); return; }
  const int hb = bx - 1;
  int i4 = hb * 256 + threadIdx.x;
  const int stride = hist_blocks * 256;
  const int E4 = E >> 2;
  for (; i4 < E4; i4 += stride) {
    const int4 d = ((const int4*)dst)[i4];
    atomicAdd(&hist[d.x], 1); atomicAdd(&hist[d.y], 1);
    atomicAdd(&hist[d.z], 1); atomicAdd(&hist[d.w], 1);
  }
  if (hb == 0) {
    int i = (E & ~3) + (int)threadIdx.x;
    if (i < E) atomicAdd(&hist[dst[i]], 1);
  }
}

__global__ __launch_bounds__(256) void scan1_k(const int* __restrict__ hist,
                                               int* __restrict__ off,
                                               int* __restrict__ parts, int N) {
  __shared__ int sh[256];
  int tid = threadIdx.x;
  int base = blockIdx.x * 1024 + tid * 4;
  int v[4], ts = 0;
#pragma unroll
  for (int j = 0; j < 4; ++j) {
    int idx = base + j;
    v[j] = (idx < N) ? hist[idx] : 0;
    ts += v[j];
  }
  sh[tid] = ts;
  __syncthreads();
  for (int o = 1; o < 256; o <<= 1) {
    int y = (tid >= o) ? sh[tid - o] : 0;
    __syncthreads();
    sh[tid] += y;
    __syncthreads();
  }
  int run = sh[tid] - ts;
#pragma unroll
  for (int j = 0; j < 4; ++j) {
    int idx = base + j;
    if (idx < N) off[idx] = run;
    run += v[j];
  }
  if (tid == 255) parts[blockIdx.x] = sh[255];
}

__global__ void scan2_k(int* __restrict__ parts, int* __restrict__ off,
                        int nparts, int N, int E) {
  int lane = threadIdx.x & 63;
  int i0 = 2 * lane, i1 = 2 * lane + 1;
  int p0 = (i0 < nparts) ? parts[i0] : 0;
  int p1 = (i1 < nparts) ? parts[i1] : 0;
  int s = p0 + p1;
  int x = s;
  for (int o = 1; o < 64; o <<= 1) {
    int y = __shfl_up(x, o);
    if (lane >= o) x += y;
  }
  int ex = x - s;
  if (i0 < nparts) parts[i0] = ex;
  if (i1 < nparts) parts[i1] = ex + p0;
  if (lane == 0) off[N] = E;
}

__global__ __launch_bounds__(256) void scan3_k(int* __restrict__ off,
                                               int* __restrict__ woff,
                                               const int* __restrict__ parts, int N) {
  int p = parts[blockIdx.x];
  int base = blockIdx.x * 1024 + threadIdx.x;
#pragma unroll
  for (int j = 0; j < 4; ++j) {
    int idx = base + j * 256;
    if (idx < N) {
      int v = off[idx] + p;
      off[idx] = v;
      woff[idx] = v;
    }
  }
}

__global__ __launch_bounds__(256) void bin_k(
    const int* __restrict__ src, const int* __restrict__ dst,
    int* __restrict__ woff, i32x2* __restrict__ packed, int E) {
  int i4 = blockIdx.x * blockDim.x + threadIdx.x;
  const int stride = gridDim.x * blockDim.x;
  const int E4 = E >> 2;
  for (; i4 < E4; i4 += stride) {
    const int4 d = ((const int4*)dst)[i4];
    const int4 s = ((const int4*)src)[i4];
    const int e0 = i4 * 4;
    int p; i32x2 v;
    p = atomicAdd(&woff[d.x], 1); v[0] = e0 + 0; v[1] = s.x; __builtin_nontemporal_store(v, &packed[p]);
    p = atomicAdd(&woff[d.y], 1); v[0] = e0 + 1; v[1] = s.y; __builtin_nontemporal_store(v, &packed[p]);
    p = atomicAdd(&woff[d.z], 1); v[0] = e0 + 2; v[1] = s.z; __builtin_nontemporal_store(v, &packed[p]);
    p = atomicAdd(&woff[d.w], 1); v[0] = e0 + 3; v[1] = s.w; __builtin_nontemporal_store(v, &packed[p]);
  }
  if (blockIdx.x == 0) {
    int i = (E & ~3) + (int)threadIdx.x;
    if (i < E) {
      int p = atomicAdd(&woff[dst[i]], 1);
      i32x2 v; v[0] = i; v[1] = src[i];
      __builtin_nontemporal_store(v, &packed[p]);
    }
  }
}

// ---- gather-reduce: wave per node, float4 lanes, 8 edges per iteration ----
__global__ __launch_bounds__(256) void reduce_k(
    const float* __restrict__ nf, const float* __restrict__ ef,
    const int* __restrict__ off, const i32x2* __restrict__ packed,
    short* __restrict__ ssum16, int N)
{
  const int wave = (blockIdx.x * blockDim.x + threadIdx.x) >> 6;
  const int lane = threadIdx.x & 63;
  if (wave >= N) return;
  const int g = lane >> 4;        // edge slot 0..3
  const int s = lane & 15;        // dim quad 0..15
  const int beg = off[wave], end = off[wave + 1];

  f32x4 anf = {0.f, 0.f, 0.f, 0.f};
  f32x4 aef = {0.f, 0.f, 0.f, 0.f};

  int i = beg;
  for (; i + 8 <= end; i += 8) {
    const i32x2 p0 = __builtin_nontemporal_load(&packed[i + g]);
    const i32x2 p1 = __builtin_nontemporal_load(&packed[i + 4 + g]);
    const f32x4 x0 = *(const f32x4*)(nf + (size_t)p0[1] * 64 + s * 4);
    const f32x4 y0 = __builtin_nontemporal_load((const f32x4*)(ef + (size_t)p0[0] * 64 + s * 4));
    const f32x4 x1 = *(const f32x4*)(nf + (size_t)p1[1] * 64 + s * 4);
    const f32x4 y1 = __builtin_nontemporal_load((const f32x4*)(ef + (size_t)p1[0] * 64 + s * 4));
    anf += x0 + x1;
    aef += y0 + y1;
  }
  if (i + 4 <= end) {
    const i32x2 p0 = __builtin_nontemporal_load(&packed[i + g]);
    const f32x4 x0 = *(const f32x4*)(nf + (size_t)p0[1] * 64 + s * 4);
    const f32x4 y0 = __builtin_nontemporal_load((const f32x4*)(ef + (size_t)p0[0] * 64 + s * 4));
    anf += x0;
    aef += y0;
    i += 4;
  }
  if (g < end - i) {
    const i32x2 p0 = __builtin_nontemporal_load(&packed[i + g]);
    const f32x4 x0 = *(const f32x4*)(nf + (size_t)p0[1] * 64 + s * 4);
    const f32x4 y0 = __builtin_nontemporal_load((const f32x4*)(ef + (size_t)p0[0] * 64 + s * 4));
    anf += x0;
    aef += y0;
  }

#pragma unroll
  for (int m = 16; m <= 32; m <<= 1) {
#pragma unroll
    for (int c = 0; c < 4; ++c) {
      anf[c] += __shfl_xor(anf[c], m);
      aef[c] += __shfl_xor(aef[c], m);
    }
  }

  short* row = ssum16 + (size_t)wave * 128;
  if (g == 0) {
    __builtin_nontemporal_store(pack4(anf), (bf16x4*)(row + s * 4));
  } else if (g == 1) {
    __builtin_nontemporal_store(pack4(aef), (bf16x4*)(row + 64 + s * 4));
  }
}

// ---- fused node GEMMs (nf read as f32, packed in-register; same f2bf) ----
// mfma_f32_16x16x32_bf16 maps: A[i][k]: lane=(k/8)*16+i, elem=k%8 ;
// B[k][j]: lane=(k/8)*16+j, elem=k%8 ; D[i][j]: lane=(i/4)*16+j, reg=i%4.
__global__ __launch_bounds__(256) void node_apply(
    const float* __restrict__ nf, const short* __restrict__ ssum16,
    const int* __restrict__ off, const short* __restrict__ wpack,
    const float* __restrict__ b_msg, const float* __restrict__ b_apply,
    float* __restrict__ out, int ntiles)
{
  __shared__ float hn[4][16 * 68];
  const int wid = threadIdx.x >> 6;
  const int lane = threadIdx.x & 63;
  const int r = lane & 15;
  const int g = lane >> 4;
  const int tile = blockIdx.x * 4 + wid;
  if (tile >= ntiles) return;
  const int n0 = tile * 16;

  bf16x8 wm[4][4], wa[4][4];
#pragma unroll
  for (int kc = 0; kc < 4; ++kc)
#pragma unroll
    for (int nc = 0; nc < 4; ++nc) {
      wm[kc][nc] = *(const bf16x8*)(wpack + ((long)((0 * 4 + kc) * 4 + nc) * 64 + lane) * 8);
      wa[kc][nc] = *(const bf16x8*)(wpack + ((long)((1 * 4 + kc) * 4 + nc) * 64 + lane) * 8);
    }

  // GEMM1: msum = ssum(16x128) @ W_msg^T
  f32x4 acc[4] = {};
#pragma unroll
  for (int kc = 0; kc < 4; ++kc) {
    const bf16x8 af = *(const bf16x8*)(ssum16 + (size_t)(n0 + r) * 128 + kc * 32 + g * 8);
#pragma unroll
    for (int nc = 0; nc < 4; ++nc)
      acc[nc] = __builtin_amdgcn_mfma_f32_16x16x32_bf16(af, wm[kc][nc], acc[nc], 0, 0, 0);
  }

  // h_neigh = cnt>0 ? msum/cnt + b_msg : 0  -> LDS (same wave, no barrier)
  float cn[4];
#pragma unroll
  for (int q = 0; q < 4; ++q) {
    int n = n0 + g * 4 + q;
    cn[q] = (float)(off[n + 1] - off[n]);
  }
#pragma unroll
  for (int nc = 0; nc < 4; ++nc) {
    const float bm = b_msg[nc * 16 + r];
#pragma unroll
    for (int q = 0; q < 4; ++q) {
      const float v = cn[q] > 0.f ? acc[nc][q] / cn[q] + bm : 0.f;
      hn[wid][(g * 4 + q) * 68 + nc * 16 + r] = v;
    }
  }

  // GEMM2: out = [nfeats ‖ h_neigh](16x128) @ W_apply^T
  f32x4 acc2[4] = {};
#pragma unroll
  for (int kc = 0; kc < 2; ++kc) {
    const float* p = nf + (size_t)(n0 + r) * 64 + kc * 32 + g * 8;
    const bf16x8 af = pack8(*(const float4*)p, *(const float4*)(p + 4));
#pragma unroll
    for (int nc = 0; nc < 4; ++nc)
      acc2[nc] = __builtin_amdgcn_mfma_f32_16x16x32_bf16(af, wa[kc][nc], acc2[nc], 0, 0, 0);
  }
#pragma unroll
  for (int kc = 2; kc < 4; ++kc) {
    const float* p = &hn[wid][r * 68 + (kc - 2) * 32 + g * 8];
    const bf16x8 af = pack8(*(const float4*)p, *(const float4*)(p + 4));
#pragma unroll
    for (int nc = 0; nc < 4; ++nc)
      acc2[nc] = __builtin_amdgcn_mfma_f32_16x16x32_bf16(af, wa[kc][nc], acc2[nc], 0, 0, 0);
  }

#pragma unroll
  for (int nc = 0; nc < 4; ++nc) {
    const float ba = b_apply[nc * 16 + r];
#pragma unroll
    for (int q = 0; q < 4; ++q) {
      float v = acc2[nc][q] + ba;
      v = v > 0.f ? v : 0.f;
      __builtin_nontemporal_store(v, &out[(size_t)(n0 + g * 4 + q) * 64 + nc * 16 + r]);
    }
  }
}

extern "C" void kernel_launch(void* const* d_in, const int* in_sizes, int n_in,
                              void* d_out, int out_size, void* d_ws, size_t ws_size,
                              hipStream_t stream) {
  const float* nfeats  = (const float*)d_in[0];
  const float* efeats  = (const float*)d_in[1];
  const int*   src     = (const int*)d_in[2];
  const int*   dst     = (const int*)d_in[3];
  const float* W_msg   = (const float*)d_in[4];
  const float* b_msg   = (const float*)d_in[5];
  const float* W_apply = (const float*)d_in[6];
  const float* b_apply = (const float*)d_in[7];
  float* out = (float*)d_out;

  int N = in_sizes[0] / 64;
  int E = in_sizes[2];

  auto alignup = [](size_t x) { return (x + 127) & ~(size_t)127; };
  char* ws = (char*)d_ws;
  size_t o = 0;
  int*  hist   = (int*)(ws + o);  o = alignup(o + (size_t)N * 4);
  int*  off    = (int*)(ws + o);  o = alignup(o + (size_t)(N + 1) * 4);
  int*  woff   = (int*)(ws + o);  o = alignup(o + (size_t)N * 4);
  int*  parts  = (int*)(ws + o);  o = alignup(o + (size_t)2048 * 4);
  i32x2* packed = (i32x2*)(ws + o); o = alignup(o + (size_t)E * 8);
  short* ssum16 = (short*)(ws + o); o = alignup(o + (size_t)N * 128 * 2);
  short* wpack  = (short*)(ws + o); o = alignup(o + (size_t)2048 * 8 * 2);

  // ---- CSR build: one cooperative kernel, fallback to discrete path ----
  void* cargs[] = {(void*)&W_msg, (void*)&W_apply, (void*)&wpack,
                   (void*)&src, (void*)&dst, (void*)&hist, (void*)&off,
                   (void*)&woff, (void*)&parts, (void*)&packed,
                   (void*)&N, (void*)&E};
  hipError_t cerr = hipLaunchCooperativeKernel(
      reinterpret_cast<void*>(csr_k), dim3(1024), dim3(256), cargs, 0, stream);
  if (cerr != hipSuccess) {
    const int nparts = (N + 1023) / 1024;
    hipMemsetAsync(hist, 0, (size_t)N * 4, stream);
    fb_histw_k<<<1 + 1024, 256, 0, stream>>>(W_msg, W_apply, wpack, dst, hist, E, 1024);
    scan1_k<<<nparts, 256, 0, stream>>>(hist, off, parts, N);
    scan2_k<<<1, 64, 0, stream>>>(parts, off, nparts, N, E);
    scan3_k<<<nparts, 256, 0, stream>>>(off, woff, parts, N);
    bin_k<<<1024, 256, 0, stream>>>(src, dst, woff, packed, E);
  }

  reduce_k<<<(N + 3) / 4, 256, 0, stream>>>(nfeats, efeats, off, packed, ssum16, N);

  const int ntiles = (N + 15) / 16;
  node_apply<<<(ntiles + 3) / 4, 256, 0, stream>>>(nfeats, ssum16, off, wpack,
                                                   b_msg, b_apply, out, ntiles);
}

// Round 12
// 646.363 us; speedup vs baseline: 1.5626x; 1.5626x over previous
//
#include <hip/hip_runtime.h>
#include <hip/hip_bf16.h>

// SAGE layer via linearity of the message Linear:
//   msum[n] = W_msg · (Σ_{e->n} [nf[src] ‖ ef[e]]) ; bias folded post-mean.
// Discrete CSR build (memset + histw + 3-stage scan + bin(int2,nt)) ->
// per-node gather-reduce (8 edges/wave-iter, nt stream loads) ->
// fused MFMA node kernel (nf packed f32->bf16 in-register; no nf16 buffer).
// NOTE: cooperative single-kernel CSR (round 10) measured 500us — grid.sync
// across 8 XCDs is ~100us+ per sync; discrete dispatch boundaries are cheaper.

typedef __attribute__((ext_vector_type(8))) short bf16x8;
typedef __attribute__((ext_vector_type(4))) short bf16x4;
typedef __attribute__((ext_vector_type(4))) float f32x4;
typedef __attribute__((ext_vector_type(2))) int i32x2;

__device__ __forceinline__ short f2bf(float f) {
  union { float f; unsigned u; } v; v.f = f;
  unsigned u = v.u;
  u += 0x7fffu + ((u >> 16) & 1u);   // round-to-nearest-even
  return (short)(u >> 16);
}

__device__ __forceinline__ bf16x8 pack8(float4 a, float4 b) {
  bf16x8 r;
  r[0] = f2bf(a.x); r[1] = f2bf(a.y); r[2] = f2bf(a.z); r[3] = f2bf(a.w);
  r[4] = f2bf(b.x); r[5] = f2bf(b.y); r[6] = f2bf(b.z); r[7] = f2bf(b.w);
  return r;
}

__device__ __forceinline__ bf16x4 pack4(f32x4 a) {
  bf16x4 r;
  r[0] = f2bf(a[0]); r[1] = f2bf(a[1]); r[2] = f2bf(a[2]); r[3] = f2bf(a[3]);
  return r;
}

__device__ __forceinline__ void pack_w_block(const float* __restrict__ Wm,
                                             const float* __restrict__ Wa,
                                             short* __restrict__ wpack, int tid) {
#pragma unroll
  for (int j = 0; j < 8; ++j) {
    int id = tid * 8 + j;
    int w = id >> 10, kc = (id >> 8) & 3, nc = (id >> 6) & 3, lane = id & 63;
    int r = lane & 15, g = lane >> 4;
    const float* W = w ? Wa : Wm;
    const float* p = W + (nc * 16 + r) * 128 + kc * 32 + g * 8;
    *(bf16x8*)(wpack + (long)id * 8) = pack8(*(const float4*)p, *(const float4*)(p + 4));
  }
}

// ---- W-pack (block 0) + dst histogram ----
__global__ __launch_bounds__(256) void histw_k(
    const float* __restrict__ Wm, const float* __restrict__ Wa,
    short* __restrict__ wpack, const int* __restrict__ dst,
    int* __restrict__ hist, int E, int hist_blocks)
{
  const int bx = (int)blockIdx.x;
  if (bx == 0) { pack_w_block(Wm, Wa, wpack, threadIdx.x); return; }
  const int hb = bx - 1;
  int i4 = hb * 256 + threadIdx.x;
  const int stride = hist_blocks * 256;
  const int E4 = E >> 2;
  for (; i4 < E4; i4 += stride) {
    const int4 d = ((const int4*)dst)[i4];
    atomicAdd(&hist[d.x], 1); atomicAdd(&hist[d.y], 1);
    atomicAdd(&hist[d.z], 1); atomicAdd(&hist[d.w], 1);
  }
  if (hb == 0) {
    int i = (E & ~3) + (int)threadIdx.x;
    if (i < E) atomicAdd(&hist[dst[i]], 1);
  }
}

// ---- CSR scan ----
__global__ __launch_bounds__(256) void scan1_k(const int* __restrict__ hist,
                                               int* __restrict__ off,
                                               int* __restrict__ parts, int N) {
  __shared__ int sh[256];
  int tid = threadIdx.x;
  int base = blockIdx.x * 1024 + tid * 4;
  int v[4], ts = 0;
#pragma unroll
  for (int j = 0; j < 4; ++j) {
    int idx = base + j;
    v[j] = (idx < N) ? hist[idx] : 0;
    ts += v[j];
  }
  sh[tid] = ts;
  __syncthreads();
  for (int o = 1; o < 256; o <<= 1) {
    int y = (tid >= o) ? sh[tid - o] : 0;
    __syncthreads();
    sh[tid] += y;
    __syncthreads();
  }
  int run = sh[tid] - ts;
#pragma unroll
  for (int j = 0; j < 4; ++j) {
    int idx = base + j;
    if (idx < N) off[idx] = run;
    run += v[j];
  }
  if (tid == 255) parts[blockIdx.x] = sh[255];
}

__global__ void scan2_k(int* __restrict__ parts, int* __restrict__ off,
                        int nparts, int N, int E) {
  int lane = threadIdx.x & 63;
  int i0 = 2 * lane, i1 = 2 * lane + 1;
  int p0 = (i0 < nparts) ? parts[i0] : 0;
  int p1 = (i1 < nparts) ? parts[i1] : 0;
  int s = p0 + p1;
  int x = s;
  for (int o = 1; o < 64; o <<= 1) {
    int y = __shfl_up(x, o);
    if (lane >= o) x += y;
  }
  int ex = x - s;
  if (i0 < nparts) parts[i0] = ex;
  if (i1 < nparts) parts[i1] = ex + p0;
  if (lane == 0) off[N] = E;
}

__global__ __launch_bounds__(256) void scan3_k(int* __restrict__ off,
                                               int* __restrict__ woff,
                                               const int* __restrict__ parts, int N) {
  int p = parts[blockIdx.x];
  int base = blockIdx.x * 1024 + threadIdx.x;
#pragma unroll
  for (int j = 0; j < 4; ++j) {
    int idx = base + j * 256;
    if (idx < N) {
      int v = off[idx] + p;
      off[idx] = v;
      woff[idx] = v;
    }
  }
}

// ---- bin: one 8B nt scattered store per edge (eid, src) ----
__global__ __launch_bounds__(256) void bin_k(
    const int* __restrict__ src, const int* __restrict__ dst,
    int* __restrict__ woff, i32x2* __restrict__ packed, int E) {
  int i4 = blockIdx.x * blockDim.x + threadIdx.x;
  const int stride = gridDim.x * blockDim.x;
  const int E4 = E >> 2;
  for (; i4 < E4; i4 += stride) {
    const int4 d = ((const int4*)dst)[i4];
    const int4 s = ((const int4*)src)[i4];
    const int e0 = i4 * 4;
    int p; i32x2 v;
    p = atomicAdd(&woff[d.x], 1); v[0] = e0 + 0; v[1] = s.x; __builtin_nontemporal_store(v, &packed[p]);
    p = atomicAdd(&woff[d.y], 1); v[0] = e0 + 1; v[1] = s.y; __builtin_nontemporal_store(v, &packed[p]);
    p = atomicAdd(&woff[d.z], 1); v[0] = e0 + 2; v[1] = s.z; __builtin_nontemporal_store(v, &packed[p]);
    p = atomicAdd(&woff[d.w], 1); v[0] = e0 + 3; v[1] = s.w; __builtin_nontemporal_store(v, &packed[p]);
  }
  if (blockIdx.x == 0) {
    int i = (E & ~3) + (int)threadIdx.x;
    if (i < E) {
      int p = atomicAdd(&woff[dst[i]], 1);
      i32x2 v; v[0] = i; v[1] = src[i];
      __builtin_nontemporal_store(v, &packed[p]);
    }
  }
}

// ---- gather-reduce: wave per node, float4 lanes, 8 edges per iteration ----
__global__ __launch_bounds__(256) void reduce_k(
    const float* __restrict__ nf, const float* __restrict__ ef,
    const int* __restrict__ off, const i32x2* __restrict__ packed,
    short* __restrict__ ssum16, int N)
{
  const int wave = (blockIdx.x * blockDim.x + threadIdx.x) >> 6;
  const int lane = threadIdx.x & 63;
  if (wave >= N) return;
  const int g = lane >> 4;        // edge slot 0..3
  const int s = lane & 15;        // dim quad 0..15
  const int beg = off[wave], end = off[wave + 1];

  f32x4 anf = {0.f, 0.f, 0.f, 0.f};
  f32x4 aef = {0.f, 0.f, 0.f, 0.f};

  int i = beg;
  for (; i + 8 <= end; i += 8) {
    const i32x2 p0 = __builtin_nontemporal_load(&packed[i + g]);
    const i32x2 p1 = __builtin_nontemporal_load(&packed[i + 4 + g]);
    const f32x4 x0 = *(const f32x4*)(nf + (size_t)p0[1] * 64 + s * 4);
    const f32x4 y0 = __builtin_nontemporal_load((const f32x4*)(ef + (size_t)p0[0] * 64 + s * 4));
    const f32x4 x1 = *(const f32x4*)(nf + (size_t)p1[1] * 64 + s * 4);
    const f32x4 y1 = __builtin_nontemporal_load((const f32x4*)(ef + (size_t)p1[0] * 64 + s * 4));
    anf += x0 + x1;
    aef += y0 + y1;
  }
  if (i + 4 <= end) {
    const i32x2 p0 = __builtin_nontemporal_load(&packed[i + g]);
    const f32x4 x0 = *(const f32x4*)(nf + (size_t)p0[1] * 64 + s * 4);
    const f32x4 y0 = __builtin_nontemporal_load((const f32x4*)(ef + (size_t)p0[0] * 64 + s * 4));
    anf += x0;
    aef += y0;
    i += 4;
  }
  if (g < end - i) {
    const i32x2 p0 = __builtin_nontemporal_load(&packed[i + g]);
    const f32x4 x0 = *(const f32x4*)(nf + (size_t)p0[1] * 64 + s * 4);
    const f32x4 y0 = __builtin_nontemporal_load((const f32x4*)(ef + (size_t)p0[0] * 64 + s * 4));
    anf += x0;
    aef += y0;
  }

#pragma unroll
  for (int m = 16; m <= 32; m <<= 1) {
#pragma unroll
    for (int c = 0; c < 4; ++c) {
      anf[c] += __shfl_xor(anf[c], m);
      aef[c] += __shfl_xor(aef[c], m);
    }
  }

  short* row = ssum16 + (size_t)wave * 128;
  if (g == 0) {
    __builtin_nontemporal_store(pack4(anf), (bf16x4*)(row + s * 4));
  } else if (g == 1) {
    __builtin_nontemporal_store(pack4(aef), (bf16x4*)(row + 64 + s * 4));
  }
}

// ---- fused node GEMMs (nf read as f32, packed in-register; same f2bf) ----
// mfma_f32_16x16x32_bf16 maps: A[i][k]: lane=(k/8)*16+i, elem=k%8 ;
// B[k][j]: lane=(k/8)*16+j, elem=k%8 ; D[i][j]: lane=(i/4)*16+j, reg=i%4.
__global__ __launch_bounds__(256) void node_apply(
    const float* __restrict__ nf, const short* __restrict__ ssum16,
    const int* __restrict__ off, const short* __restrict__ wpack,
    const float* __restrict__ b_msg, const float* __restrict__ b_apply,
    float* __restrict__ out, int ntiles)
{
  __shared__ float hn[4][16 * 68];
  const int wid = threadIdx.x >> 6;
  const int lane = threadIdx.x & 63;
  const int r = lane & 15;
  const int g = lane >> 4;
  const int tile = blockIdx.x * 4 + wid;
  if (tile >= ntiles) return;
  const int n0 = tile * 16;

  bf16x8 wm[4][4], wa[4][4];
#pragma unroll
  for (int kc = 0; kc < 4; ++kc)
#pragma unroll
    for (int nc = 0; nc < 4; ++nc) {
      wm[kc][nc] = *(const bf16x8*)(wpack + ((long)((0 * 4 + kc) * 4 + nc) * 64 + lane) * 8);
      wa[kc][nc] = *(const bf16x8*)(wpack + ((long)((1 * 4 + kc) * 4 + nc) * 64 + lane) * 8);
    }

  // GEMM1: msum = ssum(16x128) @ W_msg^T
  f32x4 acc[4] = {};
#pragma unroll
  for (int kc = 0; kc < 4; ++kc) {
    const bf16x8 af = *(const bf16x8*)(ssum16 + (size_t)(n0 + r) * 128 + kc * 32 + g * 8);
#pragma unroll
    for (int nc = 0; nc < 4; ++nc)
      acc[nc] = __builtin_amdgcn_mfma_f32_16x16x32_bf16(af, wm[kc][nc], acc[nc], 0, 0, 0);
  }

  // h_neigh = cnt>0 ? msum/cnt + b_msg : 0  -> LDS (same wave, no barrier)
  float cn[4];
#pragma unroll
  for (int q = 0; q < 4; ++q) {
    int n = n0 + g * 4 + q;
    cn[q] = (float)(off[n + 1] - off[n]);
  }
#pragma unroll
  for (int nc = 0; nc < 4; ++nc) {
    const float bm = b_msg[nc * 16 + r];
#pragma unroll
    for (int q = 0; q < 4; ++q) {
      const float v = cn[q] > 0.f ? acc[nc][q] / cn[q] + bm : 0.f;
      hn[wid][(g * 4 + q) * 68 + nc * 16 + r] = v;
    }
  }

  // GEMM2: out = [nfeats ‖ h_neigh](16x128) @ W_apply^T
  f32x4 acc2[4] = {};
#pragma unroll
  for (int kc = 0; kc < 2; ++kc) {
    const float* p = nf + (size_t)(n0 + r) * 64 + kc * 32 + g * 8;
    const bf16x8 af = pack8(*(const float4*)p, *(const float4*)(p + 4));
#pragma unroll
    for (int nc = 0; nc < 4; ++nc)
      acc2[nc] = __builtin_amdgcn_mfma_f32_16x16x32_bf16(af, wa[kc][nc], acc2[nc], 0, 0, 0);
  }
#pragma unroll
  for (int kc = 2; kc < 4; ++kc) {
    const float* p = &hn[wid][r * 68 + (kc - 2) * 32 + g * 8];
    const bf16x8 af = pack8(*(const float4*)p, *(const float4*)(p + 4));
#pragma unroll
    for (int nc = 0; nc < 4; ++nc)
      acc2[nc] = __builtin_amdgcn_mfma_f32_16x16x32_bf16(af, wa[kc][nc], acc2[nc], 0, 0, 0);
  }

#pragma unroll
  for (int nc = 0; nc < 4; ++nc) {
    const float ba = b_apply[nc * 16 + r];
#pragma unroll
    for (int q = 0; q < 4; ++q) {
      float v = acc2[nc][q] + ba;
      v = v > 0.f ? v : 0.f;
      __builtin_nontemporal_store(v, &out[(size_t)(n0 + g * 4 + q) * 64 + nc * 16 + r]);
    }
  }
}

extern "C" void kernel_launch(void* const* d_in, const int* in_sizes, int n_in,
                              void* d_out, int out_size, void* d_ws, size_t ws_size,
                              hipStream_t stream) {
  const float* nfeats  = (const float*)d_in[0];
  const float* efeats  = (const float*)d_in[1];
  const int*   src     = (const int*)d_in[2];
  const int*   dst     = (const int*)d_in[3];
  const float* W_msg   = (const float*)d_in[4];
  const float* b_msg   = (const float*)d_in[5];
  const float* W_apply = (const float*)d_in[6];
  const float* b_apply = (const float*)d_in[7];
  float* out = (float*)d_out;

  const int N = in_sizes[0] / 64;
  const int E = in_sizes[2];
  const int nparts = (N + 1023) / 1024;

  auto alignup = [](size_t x) { return (x + 127) & ~(size_t)127; };
  char* ws = (char*)d_ws;
  size_t o = 0;
  int*  hist   = (int*)(ws + o);  o = alignup(o + (size_t)N * 4);
  int*  off    = (int*)(ws + o);  o = alignup(o + (size_t)(N + 1) * 4);
  int*  woff   = (int*)(ws + o);  o = alignup(o + (size_t)N * 4);
  int*  parts  = (int*)(ws + o);  o = alignup(o + (size_t)nparts * 4);
  i32x2* packed = (i32x2*)(ws + o); o = alignup(o + (size_t)E * 8);
  short* ssum16 = (short*)(ws + o); o = alignup(o + (size_t)N * 128 * 2);
  short* wpack  = (short*)(ws + o); o = alignup(o + (size_t)2048 * 8 * 2);

  hipMemsetAsync(hist, 0, (size_t)N * 4, stream);

  histw_k<<<1 + 1024, 256, 0, stream>>>(W_msg, W_apply, wpack, dst, hist, E, 1024);
  scan1_k<<<nparts, 256, 0, stream>>>(hist, off, parts, N);
  scan2_k<<<1, 64, 0, stream>>>(parts, off, nparts, N, E);
  scan3_k<<<nparts, 256, 0, stream>>>(off, woff, parts, N);
  bin_k<<<1024, 256, 0, stream>>>(src, dst, woff, packed, E);
  reduce_k<<<(N + 3) / 4, 256, 0, stream>>>(nfeats, efeats, off, packed, ssum16, N);

  const int ntiles = (N + 15) / 16;
  node_apply<<<(ntiles + 3) / 4, 256, 0, stream>>>(nfeats, ssum16, off, wpack,
                                                   b_msg, b_apply, out, ntiles);
}